// Round 1
// baseline (765.288 us; speedup 1.0000x reference)
//
#include <hip/hip_runtime.h>
#include <math.h>

#define ALPHA 50.0f
#define EPS 1e-12f

constexpr int N = 64, C = 128, P = 4096, K = 64;

// ---------------------------------------------------------------------------
// Kernel 1: per-pixel channel-norm + logits GEMM (x^n . Wn), writes logits to
// d_out and 1/||x|| to ws. One thread = one pixel, loop over c with coalesced
// global loads; Wn staged (and column-normalized) in LDS, float4 reads.
// ---------------------------------------------------------------------------
__global__ __launch_bounds__(256) void k_logits(
    const float* __restrict__ x, const float* __restrict__ W,
    float* __restrict__ logits, float* __restrict__ invn)
{
    __shared__ float Wn[C * K];      // 32 KiB, layout [c][k]
    __shared__ float colinv[K];
    const int tid = threadIdx.x;

    #pragma unroll
    for (int idx = tid; idx < C * K; idx += 256) Wn[idx] = W[idx];
    __syncthreads();
    if (tid < K) {
        float s = 0.f;
        for (int c = 0; c < C; ++c) { float v = Wn[c * K + tid]; s = fmaf(v, v, s); }
        colinv[tid] = 1.0f / fmaxf(sqrtf(s), EPS);
    }
    __syncthreads();
    #pragma unroll
    for (int idx = tid; idx < C * K; idx += 256) Wn[idx] *= colinv[idx & (K - 1)];
    __syncthreads();

    const int bx = blockIdx.x;
    const int n = bx >> 4;                    // P/256 = 16 pixel-tiles per n
    const int p = ((bx & 15) << 8) + tid;

    const float* xp = x + (size_t)n * C * P + p;
    float acc[K];
    #pragma unroll
    for (int k = 0; k < K; ++k) acc[k] = 0.f;
    float ss = 0.f;

    const float4* Wn4 = (const float4*)Wn;
    for (int c = 0; c < C; ++c) {
        float xv = xp[(size_t)c * P];
        ss = fmaf(xv, xv, ss);
        #pragma unroll
        for (int kk = 0; kk < K / 4; ++kk) {
            float4 w = Wn4[c * (K / 4) + kk];
            acc[kk * 4 + 0] = fmaf(xv, w.x, acc[kk * 4 + 0]);
            acc[kk * 4 + 1] = fmaf(xv, w.y, acc[kk * 4 + 1]);
            acc[kk * 4 + 2] = fmaf(xv, w.z, acc[kk * 4 + 2]);
            acc[kk * 4 + 3] = fmaf(xv, w.w, acc[kk * 4 + 3]);
        }
    }
    const float inv = 1.0f / fmaxf(sqrtf(ss), EPS);
    invn[(size_t)n * P + p] = inv;
    float* lp = logits + (size_t)n * K * P + p;
    #pragma unroll
    for (int k = 0; k < K; ++k) lp[(size_t)k * P] = acc[k] * inv;
}

// ---------------------------------------------------------------------------
// Kernel 2: vlad partial GEMM: vlad_raw[n,k,c] += sum_p sa[n,k,p]*xn[n,c,p].
// Recomputes softmax from logits (read back from d_out) in LDS; accumulates
// S[n,k] = sum_p sa as byproduct. Register tile 4k x 8c per thread.
// ---------------------------------------------------------------------------
constexpr int TP  = 64;        // pixels per LDS tile
constexpr int LST = TP + 1;    // padded stride (bank-conflict free)
constexpr int PCH = 512;       // pixels per block
constexpr int TILES = PCH / TP;

__global__ __launch_bounds__(256) void k_vlad(
    const float* __restrict__ x, const float* __restrict__ logits,
    const float* __restrict__ bias, const float* __restrict__ invn,
    float* __restrict__ vlad_raw, float* __restrict__ Ssum)
{
    __shared__ float sa[K * LST];     // 16.25 KiB
    __shared__ float xn[C * LST];     // 32.5 KiB
    __shared__ float invs[TP];
    __shared__ float biass[K];

    const int tid = threadIdx.x;
    const int bx  = blockIdx.x;
    const int n = bx >> 3;                 // P/PCH = 8 chunks per n
    const int p0base = (bx & 7) * PCH;

    if (tid < K) biass[tid] = bias[tid];

    const int kg = tid >> 4;   // 16 k-groups of 4
    const int cg = tid & 15;   // 16 c-groups of 8
    float facc[32];
    #pragma unroll
    for (int i = 0; i < 32; ++i) facc[i] = 0.f;
    float Sloc = 0.f;

    for (int t = 0; t < TILES; ++t) {
        const int p0 = p0base + t * TP;
        __syncthreads();                     // protect LDS vs previous MAC
        if (tid < TP) invs[tid] = invn[(size_t)n * P + p0 + tid];
        #pragma unroll
        for (int r = 0; r < K * TP / 256; ++r) {       // logits -> LDS
            int idx = r * 256 + tid;
            int k = idx >> 6, i = idx & 63;
            sa[k * LST + i] = logits[(size_t)(n * K + k) * P + p0 + i];
        }
        __syncthreads();
        #pragma unroll
        for (int r = 0; r < C * TP / 256; ++r) {       // x (normalized) -> LDS
            int idx = r * 256 + tid;
            int c = idx >> 6, i = idx & 63;
            xn[c * LST + i] = x[(size_t)(n * C + c) * P + p0 + i] * invs[i];
        }
        if (tid < TP) {                                // softmax over k, col i
            const int i = tid;
            float m = -1e30f;
            for (int k = 0; k < K; ++k) {
                float v = (sa[k * LST + i] + biass[k]) * ALPHA;
                m = fmaxf(m, v);
            }
            float sum = 0.f;
            for (int k = 0; k < K; ++k) {
                float v = (sa[k * LST + i] + biass[k]) * ALPHA;
                float e = __expf(v - m);
                sa[k * LST + i] = e;
                sum += e;
            }
            float r = 1.0f / sum;
            for (int k = 0; k < K; ++k) sa[k * LST + i] *= r;
        }
        __syncthreads();
        if (tid < K) {                                 // S partial (row sums)
            float s = 0.f;
            for (int i = 0; i < TP; ++i) s += sa[tid * LST + i];
            Sloc += s;
        }
        #pragma unroll 2
        for (int i = 0; i < TP; ++i) {                 // MAC: 4k x 8c
            float a0 = sa[(kg * 4 + 0) * LST + i];
            float a1 = sa[(kg * 4 + 1) * LST + i];
            float a2 = sa[(kg * 4 + 2) * LST + i];
            float a3 = sa[(kg * 4 + 3) * LST + i];
            float xv[8];
            #pragma unroll
            for (int l = 0; l < 8; ++l) xv[l] = xn[(cg * 8 + l) * LST + i];
            #pragma unroll
            for (int l = 0; l < 8; ++l) {
                facc[0 * 8 + l] = fmaf(a0, xv[l], facc[0 * 8 + l]);
                facc[1 * 8 + l] = fmaf(a1, xv[l], facc[1 * 8 + l]);
                facc[2 * 8 + l] = fmaf(a2, xv[l], facc[2 * 8 + l]);
                facc[3 * 8 + l] = fmaf(a3, xv[l], facc[3 * 8 + l]);
            }
        }
    }

    float* vr = vlad_raw + (size_t)n * K * C;
    #pragma unroll
    for (int j = 0; j < 4; ++j)
        #pragma unroll
        for (int l = 0; l < 8; ++l)
            atomicAdd(&vr[(kg * 4 + j) * C + (cg * 8 + l)], facc[j * 8 + l]);
    if (tid < K) atomicAdd(&Ssum[n * K + tid], Sloc);
}

// ---------------------------------------------------------------------------
// Kernel 3: vlad = l2norm_global(l2norm_c(raw - W[c,k]*S[n,k])). One block/n.
// ---------------------------------------------------------------------------
__global__ __launch_bounds__(256) void k_post(
    const float* __restrict__ vlad_raw, const float* __restrict__ W,
    const float* __restrict__ Ssum, float* __restrict__ out)
{
    __shared__ float red[256];
    const int tid = threadIdx.x;
    const int n = blockIdx.x;
    const int k = tid >> 2;        // 64 rows
    const int part = tid & 3;      // 4 threads per row
    const int c0 = part * 32;

    const float* vr = vlad_raw + (size_t)n * K * C + k * C + c0;
    const float Sk = Ssum[n * K + k];
    float v[32];
    float ss = 0.f;
    #pragma unroll
    for (int l = 0; l < 32; ++l) {
        float val = vr[l] - W[(size_t)(c0 + l) * K + k] * Sk;
        v[l] = val;
        ss = fmaf(val, val, ss);
    }
    ss += __shfl_xor(ss, 1);
    ss += __shfl_xor(ss, 2);
    const float inv1 = 1.0f / fmaxf(sqrtf(ss), EPS);
    float ss2 = 0.f;
    #pragma unroll
    for (int l = 0; l < 32; ++l) { v[l] *= inv1; ss2 = fmaf(v[l], v[l], ss2); }
    red[tid] = ss2;
    __syncthreads();
    for (int s = 128; s > 0; s >>= 1) {
        if (tid < s) red[tid] += red[tid + s];
        __syncthreads();
    }
    const float inv2 = 1.0f / fmaxf(sqrtf(red[0]), EPS);
    float* op = out + (size_t)n * K * C + k * C + c0;
    #pragma unroll
    for (int l = 0; l < 32; ++l) op[l] = v[l] * inv2;
}

// ---------------------------------------------------------------------------
extern "C" void kernel_launch(void* const* d_in, const int* in_sizes, int n_in,
                              void* d_out, int out_size, void* d_ws, size_t ws_size,
                              hipStream_t stream)
{
    const float* x    = (const float*)d_in[0];
    const float* W    = (const float*)d_in[1];
    const float* bias = (const float*)d_in[2];

    float* out_vlad   = (float*)d_out;                       // N*K*C
    float* out_logits = (float*)d_out + (size_t)N * K * C;   // N*K*P

    float* invn     = (float*)d_ws;                          // N*P floats
    float* Ssum     = invn + (size_t)N * P;                  // N*K floats
    float* vlad_raw = Ssum + (size_t)N * K;                  // N*K*C floats

    hipMemsetAsync(Ssum, 0, (size_t)(N * K + N * K * C) * sizeof(float), stream);
    k_logits<<<dim3(N * (P / 256)), dim3(256), 0, stream>>>(x, W, out_logits, invn);
    k_vlad<<<dim3(N * (P / PCH)), dim3(256), 0, stream>>>(x, out_logits, bias, invn, vlad_raw, Ssum);
    k_post<<<dim3(N), dim3(256), 0, stream>>>(vlad_raw, W, Ssum, out_vlad);
}

// Round 2
// 378.934 us; speedup vs baseline: 2.0196x; 2.0196x over previous
//
#include <hip/hip_runtime.h>
#include <math.h>

#define ALPHA 50.0f
#define EPS 1e-12f

constexpr int N = 64, C = 128, P = 4096, K = 64;

// ---------------------------------------------------------------------------
// Kernel 1: per-pixel channel-norm + logits GEMM (x^n . Wn), writes logits to
// d_out and 1/||x|| to ws. One thread = one pixel; Wn staged (and
// column-normalized) in LDS, float4 broadcast reads.
// ---------------------------------------------------------------------------
__global__ __launch_bounds__(256) void k_logits(
    const float* __restrict__ x, const float* __restrict__ W,
    float* __restrict__ logits, float* __restrict__ invn)
{
    __shared__ float Wn[C * K];      // 32 KiB, layout [c][k]
    __shared__ float colinv[K];
    const int tid = threadIdx.x;

    #pragma unroll
    for (int idx = tid; idx < C * K; idx += 256) Wn[idx] = W[idx];
    __syncthreads();
    if (tid < K) {
        float s = 0.f;
        for (int c = 0; c < C; ++c) { float v = Wn[c * K + tid]; s = fmaf(v, v, s); }
        colinv[tid] = 1.0f / fmaxf(sqrtf(s), EPS);
    }
    __syncthreads();
    #pragma unroll
    for (int idx = tid; idx < C * K; idx += 256) Wn[idx] *= colinv[idx & (K - 1)];
    __syncthreads();

    const int bx = blockIdx.x;
    const int n = bx >> 4;                    // P/256 = 16 pixel-tiles per n
    const int p = ((bx & 15) << 8) + tid;

    const float* xp = x + (size_t)n * C * P + p;
    float acc[K];
    #pragma unroll
    for (int k = 0; k < K; ++k) acc[k] = 0.f;
    float ss = 0.f;

    const float4* Wn4 = (const float4*)Wn;
    for (int c = 0; c < C; ++c) {
        float xv = xp[(size_t)c * P];
        ss = fmaf(xv, xv, ss);
        #pragma unroll
        for (int kk = 0; kk < K / 4; ++kk) {
            float4 w = Wn4[c * (K / 4) + kk];
            acc[kk * 4 + 0] = fmaf(xv, w.x, acc[kk * 4 + 0]);
            acc[kk * 4 + 1] = fmaf(xv, w.y, acc[kk * 4 + 1]);
            acc[kk * 4 + 2] = fmaf(xv, w.z, acc[kk * 4 + 2]);
            acc[kk * 4 + 3] = fmaf(xv, w.w, acc[kk * 4 + 3]);
        }
    }
    const float inv = 1.0f / fmaxf(sqrtf(ss), EPS);
    invn[(size_t)n * P + p] = inv;
    float* lp = logits + (size_t)n * K * P + p;
    #pragma unroll
    for (int k = 0; k < K; ++k) lp[(size_t)k * P] = acc[k] * inv;
}

// ---------------------------------------------------------------------------
// Kernel 2: vlad partial GEMM: vlad_raw[n,k,c] += sum_p sa[n,k,p]*xn[n,c,p].
// Softmax recomputed from logits with ALL 256 threads (no max-subtraction:
// |logit|<=1 so |50*logit|<=50, exp(+-50) is safe in fp32). Conflict-free LDS:
// sa stride 66, xn stride 68, c-mapping cg+16*l. float2 MAC reads.
// ---------------------------------------------------------------------------
constexpr int TP  = 64;        // pixels per LDS tile
constexpr int SAS = 66;        // sa row stride (8B aligned rows, 2k+i banks)
constexpr int XNS = 68;        // xn row stride (16B aligned rows, 4cg banks)
constexpr int PCH = 256;       // pixels per block
constexpr int TILES = PCH / TP;

__global__ __launch_bounds__(256) void k_vlad(
    const float* __restrict__ x, const float* __restrict__ logits,
    const float* __restrict__ bias, const float* __restrict__ invn,
    float* __restrict__ vlad_raw, float* __restrict__ Ssum)
{
    __shared__ float sa[K * SAS];     // 16.5 KiB
    __shared__ float xn[C * XNS];     // 34 KiB
    __shared__ float red[256];
    __shared__ float rfin[TP];
    __shared__ float biass[K];

    const int tid = threadIdx.x;
    const int n  = blockIdx.x >> 4;                // P/PCH = 16 chunks per n
    const int p0 = (blockIdx.x & 15) * PCH;

    if (tid < K) biass[tid] = bias[tid];

    const int kg = tid >> 4;   // 16 k-groups of 4
    const int cg = tid & 15;   // c = cg + 16*l  (conflict-free in MAC)
    const int si = tid & 63;   // softmax column / S row
    const int sq = tid >> 6;   // quarter

    float facc[32];
    #pragma unroll
    for (int i = 0; i < 32; ++i) facc[i] = 0.f;
    float Sreg = 0.f;

    for (int t = 0; t < TILES; ++t) {
        const int pb = p0 + t * TP;
        __syncthreads();                           // LDS reuse guard
        #pragma unroll
        for (int r = 0; r < 8; ++r) {              // logits -> sa (float2)
            int idx = r * 256 + tid;
            int k = idx >> 5, f = idx & 31;
            float2 v = *(const float2*)&logits[(size_t)(n * K + k) * P + pb + 2 * f];
            *(float2*)&sa[k * SAS + 2 * f] = v;
        }
        #pragma unroll
        for (int r = 0; r < 8; ++r) {              // x (normalized) -> xn (float4)
            int idx = r * 256 + tid;
            int c = idx >> 4, f = idx & 15;
            float4 v  = *(const float4*)&x[(size_t)(n * C + c) * P + pb + 4 * f];
            float4 iv = *(const float4*)&invn[(size_t)n * P + pb + 4 * f];
            v.x *= iv.x; v.y *= iv.y; v.z *= iv.z; v.w *= iv.w;
            *(float4*)&xn[c * XNS + 4 * f] = v;
        }
        __syncthreads();
        // --- softmax over k, 4 threads per column ---
        float psum = 0.f;
        #pragma unroll
        for (int kk = 0; kk < 16; ++kk) {
            int k = sq * 16 + kk;
            float e = __expf((sa[k * SAS + si] + biass[k]) * ALPHA);
            sa[k * SAS + si] = e;
            psum += e;
        }
        red[tid] = psum;
        __syncthreads();
        if (sq == 0) rfin[si] = 1.0f / (red[si] + red[64 + si] + red[128 + si] + red[192 + si]);
        __syncthreads();
        {
            float r = rfin[si];
            #pragma unroll
            for (int kk = 0; kk < 16; ++kk) sa[(sq * 16 + kk) * SAS + si] *= r;
        }
        __syncthreads();
        // --- S partials: row si, columns [sq*16, sq*16+16) ---
        {
            float s = 0.f;
            #pragma unroll
            for (int ii = 0; ii < 16; ++ii) s += sa[si * SAS + sq * 16 + ii];
            Sreg += s;
        }
        // --- MAC: 4k x 8c per thread, float2 along i ---
        #pragma unroll 4
        for (int ii = 0; ii < TP / 2; ++ii) {
            float2 a[4];
            #pragma unroll
            for (int j = 0; j < 4; ++j)
                a[j] = *(const float2*)&sa[(kg * 4 + j) * SAS + 2 * ii];
            float2 xv[8];
            #pragma unroll
            for (int l = 0; l < 8; ++l)
                xv[l] = *(const float2*)&xn[(cg + 16 * l) * XNS + 2 * ii];
            #pragma unroll
            for (int j = 0; j < 4; ++j)
                #pragma unroll
                for (int l = 0; l < 8; ++l) {
                    facc[j * 8 + l] = fmaf(a[j].x, xv[l].x, facc[j * 8 + l]);
                    facc[j * 8 + l] = fmaf(a[j].y, xv[l].y, facc[j * 8 + l]);
                }
        }
    }

    float* vr = vlad_raw + (size_t)n * K * C;
    #pragma unroll
    for (int j = 0; j < 4; ++j)
        #pragma unroll
        for (int l = 0; l < 8; ++l)
            atomicAdd(&vr[(kg * 4 + j) * C + (cg + 16 * l)], facc[j * 8 + l]);
    atomicAdd(&Ssum[n * K + si], Sreg);
}

// ---------------------------------------------------------------------------
// Kernel 3: vlad = l2norm_global(l2norm_c(raw - W[c,k]*S[n,k])). One block/n.
// ---------------------------------------------------------------------------
__global__ __launch_bounds__(256) void k_post(
    const float* __restrict__ vlad_raw, const float* __restrict__ W,
    const float* __restrict__ Ssum, float* __restrict__ out)
{
    __shared__ float red[256];
    const int tid = threadIdx.x;
    const int n = blockIdx.x;
    const int k = tid >> 2;        // 64 rows
    const int part = tid & 3;      // 4 threads per row
    const int c0 = part * 32;

    const float* vr = vlad_raw + (size_t)n * K * C + k * C + c0;
    const float Sk = Ssum[n * K + k];
    float v[32];
    float ss = 0.f;
    #pragma unroll
    for (int l = 0; l < 32; ++l) {
        float val = vr[l] - W[(size_t)(c0 + l) * K + k] * Sk;
        v[l] = val;
        ss = fmaf(val, val, ss);
    }
    ss += __shfl_xor(ss, 1);
    ss += __shfl_xor(ss, 2);
    const float inv1 = 1.0f / fmaxf(sqrtf(ss), EPS);
    float ss2 = 0.f;
    #pragma unroll
    for (int l = 0; l < 32; ++l) { v[l] *= inv1; ss2 = fmaf(v[l], v[l], ss2); }
    red[tid] = ss2;
    __syncthreads();
    for (int s = 128; s > 0; s >>= 1) {
        if (tid < s) red[tid] += red[tid + s];
        __syncthreads();
    }
    const float inv2 = 1.0f / fmaxf(sqrtf(red[0]), EPS);
    float* op = out + (size_t)n * K * C + k * C + c0;
    #pragma unroll
    for (int l = 0; l < 32; ++l) op[l] = v[l] * inv2;
}

// ---------------------------------------------------------------------------
extern "C" void kernel_launch(void* const* d_in, const int* in_sizes, int n_in,
                              void* d_out, int out_size, void* d_ws, size_t ws_size,
                              hipStream_t stream)
{
    const float* x    = (const float*)d_in[0];
    const float* W    = (const float*)d_in[1];
    const float* bias = (const float*)d_in[2];

    float* out_vlad   = (float*)d_out;                       // N*K*C
    float* out_logits = (float*)d_out + (size_t)N * K * C;   // N*K*P

    float* invn     = (float*)d_ws;                          // N*P floats
    float* Ssum     = invn + (size_t)N * P;                  // N*K floats
    float* vlad_raw = Ssum + (size_t)N * K;                  // N*K*C floats

    hipMemsetAsync(Ssum, 0, (size_t)(N * K + N * K * C) * sizeof(float), stream);
    k_logits<<<dim3(N * (P / 256)), dim3(256), 0, stream>>>(x, W, out_logits, invn);
    k_vlad<<<dim3(N * (P / PCH)), dim3(256), 0, stream>>>(x, out_logits, bias, invn, vlad_raw, Ssum);
    k_post<<<dim3(N), dim3(256), 0, stream>>>(vlad_raw, W, Ssum, out_vlad);
}

// Round 3
// 374.075 us; speedup vs baseline: 2.0458x; 1.0130x over previous
//
#include <hip/hip_runtime.h>
#include <math.h>

#define ALPHA 50.0f
#define EPS 1e-12f

constexpr int N = 64, C = 128, P = 4096, K = 64;
constexpr int PCH = 512;            // pixels per k_vlad block
constexpr int NCH = P / PCH;        // 8 chunks per image

// ---------------------------------------------------------------------------
// Kernel 1: per-pixel channel-norm + logits GEMM. 2 adjacent pixels per thread
// (float2) so each Wn LDS broadcast feeds 8 FMAs -> VALU-bound, not LDS-bound.
// ---------------------------------------------------------------------------
__global__ __launch_bounds__(256) void k_logits(
    const float* __restrict__ x, const float* __restrict__ W,
    float* __restrict__ logits, float* __restrict__ invn)
{
    __shared__ float Wn[C * K];      // 32 KiB, [c][k]
    __shared__ float colinv[K];
    const int tid = threadIdx.x;

    for (int idx = tid; idx < C * K; idx += 256) Wn[idx] = W[idx];
    __syncthreads();
    if (tid < K) {
        float s = 0.f;
        for (int c = 0; c < C; ++c) { float v = Wn[c * K + tid]; s = fmaf(v, v, s); }
        colinv[tid] = 1.0f / fmaxf(sqrtf(s), EPS);
    }
    __syncthreads();
    for (int idx = tid; idx < C * K; idx += 256) Wn[idx] *= colinv[idx & (K - 1)];
    __syncthreads();

    const int n  = blockIdx.x >> 3;           // 8 pixel-tiles of 512 per n
    const int p  = (blockIdx.x & 7) * 512 + 2 * tid;

    const float* xp = x + (size_t)n * C * P + p;
    float2 acc[K];
    #pragma unroll
    for (int k = 0; k < K; ++k) { acc[k].x = 0.f; acc[k].y = 0.f; }
    float2 ss; ss.x = 0.f; ss.y = 0.f;

    const float4* Wn4 = (const float4*)Wn;
    for (int c = 0; c < C; ++c) {
        float2 xv = *(const float2*)&xp[(size_t)c * P];
        ss.x = fmaf(xv.x, xv.x, ss.x);
        ss.y = fmaf(xv.y, xv.y, ss.y);
        #pragma unroll
        for (int kk = 0; kk < 16; ++kk) {
            float4 w = Wn4[c * 16 + kk];
            acc[kk * 4 + 0].x = fmaf(xv.x, w.x, acc[kk * 4 + 0].x);
            acc[kk * 4 + 0].y = fmaf(xv.y, w.x, acc[kk * 4 + 0].y);
            acc[kk * 4 + 1].x = fmaf(xv.x, w.y, acc[kk * 4 + 1].x);
            acc[kk * 4 + 1].y = fmaf(xv.y, w.y, acc[kk * 4 + 1].y);
            acc[kk * 4 + 2].x = fmaf(xv.x, w.z, acc[kk * 4 + 2].x);
            acc[kk * 4 + 2].y = fmaf(xv.y, w.z, acc[kk * 4 + 2].y);
            acc[kk * 4 + 3].x = fmaf(xv.x, w.w, acc[kk * 4 + 3].x);
            acc[kk * 4 + 3].y = fmaf(xv.y, w.w, acc[kk * 4 + 3].y);
        }
    }
    float2 inv;
    inv.x = 1.0f / fmaxf(sqrtf(ss.x), EPS);
    inv.y = 1.0f / fmaxf(sqrtf(ss.y), EPS);
    *(float2*)&invn[(size_t)n * P + p] = inv;
    float* lp = logits + (size_t)n * K * P + p;
    #pragma unroll
    for (int k = 0; k < K; ++k) {
        float2 o; o.x = acc[k].x * inv.x; o.y = acc[k].y * inv.y;
        *(float2*)&lp[(size_t)k * P] = o;
    }
}

// ---------------------------------------------------------------------------
// Kernel 2: vlad partial GEMM, no atomics: per-chunk partials to ws.
// LDS stride 68 floats = 17 x 16B (odd 16B stride) -> conflict-free b128.
// float4 MAC: 12 ds_read_b128 per 128 FMAs -> VALU-bound.
// ---------------------------------------------------------------------------
constexpr int TP  = 64;
constexpr int STR = 68;
constexpr int TILES = PCH / TP;

__global__ __launch_bounds__(256) void k_vlad(
    const float* __restrict__ x, const float* __restrict__ logits,
    const float* __restrict__ bias, const float* __restrict__ invn,
    float* __restrict__ vlad_part, float* __restrict__ Spart)
{
    __shared__ float sa[K * STR];     // 17 KiB
    __shared__ float xn[C * STR];     // 34 KiB
    __shared__ float red[256];
    __shared__ float biass[K];

    const int tid = threadIdx.x;
    const int n  = blockIdx.x >> 3;
    const int ch = blockIdx.x & 7;
    const int p0 = ch * PCH;

    if (tid < K) biass[tid] = bias[tid];

    const int kg = tid >> 4;   // 16 k-groups of 4
    const int cg = tid & 15;   // c = cg + 16*l
    const int si = tid & 63;   // softmax pixel column / S row
    const int sq = tid >> 6;   // quarter

    float facc[32];
    #pragma unroll
    for (int i = 0; i < 32; ++i) facc[i] = 0.f;
    float Sreg = 0.f;

    for (int t = 0; t < TILES; ++t) {
        const int pb = p0 + t * TP;
        __syncthreads();                           // LDS reuse guard
        #pragma unroll
        for (int r = 0; r < 4; ++r) {              // logits -> sa (float4)
            int idx = r * 256 + tid;
            int k = idx >> 4, f = idx & 15;
            float4 v = *(const float4*)&logits[(size_t)(n * K + k) * P + pb + 4 * f];
            *(float4*)&sa[k * STR + 4 * f] = v;
        }
        #pragma unroll
        for (int r = 0; r < 8; ++r) {              // x * invn -> xn (float4)
            int idx = r * 256 + tid;
            int c = idx >> 4, f = idx & 15;
            float4 v  = *(const float4*)&x[(size_t)(n * C + c) * P + pb + 4 * f];
            float4 iv = *(const float4*)&invn[(size_t)n * P + pb + 4 * f];
            v.x *= iv.x; v.y *= iv.y; v.z *= iv.z; v.w *= iv.w;
            *(float4*)&xn[c * STR + 4 * f] = v;
        }
        __syncthreads();
        // --- softmax over k, 4 threads per pixel column ---
        float psum = 0.f;
        #pragma unroll
        for (int kk = 0; kk < 16; ++kk) {
            int k = sq * 16 + kk;
            float e = __expf((sa[k * STR + si] + biass[k]) * ALPHA);
            sa[k * STR + si] = e;
            psum += e;
        }
        red[tid] = psum;
        __syncthreads();
        {
            float r = 1.0f / (red[si] + red[64 + si] + red[128 + si] + red[192 + si]);
            #pragma unroll
            for (int kk = 0; kk < 16; ++kk) sa[(sq * 16 + kk) * STR + si] *= r;
        }
        __syncthreads();
        // --- S partial: row k=si, pixels [16*sq, 16*sq+16) ---
        {
            float s = 0.f;
            #pragma unroll
            for (int ii = 0; ii < 16; ++ii) s += sa[si * STR + sq * 16 + ii];
            Sreg += s;
        }
        // --- MAC: 4k x 8c x 4px per iteration ---
        #pragma unroll 2
        for (int ii = 0; ii < TP / 4; ++ii) {
            float4 a[4];
            #pragma unroll
            for (int j = 0; j < 4; ++j)
                a[j] = *(const float4*)&sa[(kg * 4 + j) * STR + 4 * ii];
            float4 xv[8];
            #pragma unroll
            for (int l = 0; l < 8; ++l)
                xv[l] = *(const float4*)&xn[(cg + 16 * l) * STR + 4 * ii];
            #pragma unroll
            for (int j = 0; j < 4; ++j)
                #pragma unroll
                for (int l = 0; l < 8; ++l) {
                    facc[j * 8 + l] = fmaf(a[j].x, xv[l].x, facc[j * 8 + l]);
                    facc[j * 8 + l] = fmaf(a[j].y, xv[l].y, facc[j * 8 + l]);
                    facc[j * 8 + l] = fmaf(a[j].z, xv[l].z, facc[j * 8 + l]);
                    facc[j * 8 + l] = fmaf(a[j].w, xv[l].w, facc[j * 8 + l]);
                }
        }
    }

    float* vp = vlad_part + ((size_t)(ch * N + n)) * K * C;
    #pragma unroll
    for (int j = 0; j < 4; ++j)
        #pragma unroll
        for (int l = 0; l < 8; ++l)
            vp[(kg * 4 + j) * C + (cg + 16 * l)] = facc[j * 8 + l];

    red[tid] = Sreg;
    __syncthreads();
    if (sq == 0)
        Spart[(size_t)(ch * N + n) * K + si] =
            red[si] + red[64 + si] + red[128 + si] + red[192 + si];
}

// ---------------------------------------------------------------------------
// Kernel 3: reduce 8 chunk-partials, subtract W*S, intra-norm, global norm.
// ---------------------------------------------------------------------------
__global__ __launch_bounds__(256) void k_post(
    const float* __restrict__ vlad_part, const float* __restrict__ W,
    const float* __restrict__ Spart, float* __restrict__ out)
{
    __shared__ float red[256];
    const int tid = threadIdx.x;
    const int n = blockIdx.x;
    const int k = tid >> 2;        // 64 rows
    const int part = tid & 3;      // 4 threads per row
    const int c0 = part * 32;

    float Sk = 0.f;
    #pragma unroll
    for (int ch = 0; ch < NCH; ++ch) Sk += Spart[(size_t)(ch * N + n) * K + k];

    float v[32];
    #pragma unroll
    for (int l = 0; l < 32; ++l) v[l] = 0.f;
    #pragma unroll
    for (int ch = 0; ch < NCH; ++ch) {
        const float* vp = vlad_part + ((size_t)(ch * N + n) * K + k) * C + c0;
        #pragma unroll
        for (int l4 = 0; l4 < 8; ++l4) {
            float4 t = *(const float4*)&vp[4 * l4];
            v[4 * l4 + 0] += t.x; v[4 * l4 + 1] += t.y;
            v[4 * l4 + 2] += t.z; v[4 * l4 + 3] += t.w;
        }
    }

    float ss = 0.f;
    #pragma unroll
    for (int l = 0; l < 32; ++l) {
        float val = v[l] - W[(size_t)(c0 + l) * K + k] * Sk;
        v[l] = val;
        ss = fmaf(val, val, ss);
    }
    ss += __shfl_xor(ss, 1);
    ss += __shfl_xor(ss, 2);
    const float inv1 = 1.0f / fmaxf(sqrtf(ss), EPS);
    float ss2 = 0.f;
    #pragma unroll
    for (int l = 0; l < 32; ++l) { v[l] *= inv1; ss2 = fmaf(v[l], v[l], ss2); }
    red[tid] = ss2;
    __syncthreads();
    for (int s = 128; s > 0; s >>= 1) {
        if (tid < s) red[tid] += red[tid + s];
        __syncthreads();
    }
    const float inv2 = 1.0f / fmaxf(sqrtf(red[0]), EPS);
    float* op = out + (size_t)n * K * C + k * C + c0;
    #pragma unroll
    for (int l = 0; l < 32; ++l) op[l] = v[l] * inv2;
}

// ---------------------------------------------------------------------------
extern "C" void kernel_launch(void* const* d_in, const int* in_sizes, int n_in,
                              void* d_out, int out_size, void* d_ws, size_t ws_size,
                              hipStream_t stream)
{
    const float* x    = (const float*)d_in[0];
    const float* W    = (const float*)d_in[1];
    const float* bias = (const float*)d_in[2];

    float* out_vlad   = (float*)d_out;                       // N*K*C
    float* out_logits = (float*)d_out + (size_t)N * K * C;   // N*K*P

    float* invn      = (float*)d_ws;                         // N*P
    float* Spart     = invn + (size_t)N * P;                 // NCH*N*K
    float* vlad_part = Spart + (size_t)NCH * N * K;          // NCH*N*K*C

    k_logits<<<dim3(N * 8), dim3(256), 0, stream>>>(x, W, out_logits, invn);
    k_vlad<<<dim3(N * NCH), dim3(256), 0, stream>>>(x, out_logits, bias, invn, vlad_part, Spart);
    k_post<<<dim3(N), dim3(256), 0, stream>>>(vlad_part, W, Spart, out_vlad);
}

// Round 4
// 321.364 us; speedup vs baseline: 2.3814x; 1.1640x over previous
//
#include <hip/hip_runtime.h>
#include <math.h>

#define ALPHA 50.0f
#define EPS 1e-12f

constexpr int N = 64, C = 128, P = 4096, K = 64;

// ---------------------------------------------------------------------------
// Kernel 1: logits GEMM, register-tiled. Block: 128 px x 64 k, full C sweep
// in chunks of BC=32 staged in LDS. Thread tile: 8 px x 4 k (acc 32 regs).
// Per c: 2 b128 px-frag + 1 b128 w-frag -> 40 FMA (incl 8 sumsq).
// Normalization commutes: logits = (x . Wn) * invn[px], invn from sumsq
// accumulated in the same sweep.
// ---------------------------------------------------------------------------
constexpr int BC  = 32;          // c per LDS chunk
constexpr int PXB = 128;         // px per block
constexpr int XSTR = PXB + 4;    // xs row stride (dwords)

__global__ __launch_bounds__(256) void k_logits(
    const float* __restrict__ x, const float* __restrict__ W,
    float* __restrict__ logits, float* __restrict__ invn)
{
    __shared__ float Wn[C * K];        // 32 KiB, [c][k]
    __shared__ float colinv[K];
    __shared__ float xs[BC * XSTR];    // 16.9 KiB

    const int tid = threadIdx.x;

    for (int idx = tid; idx < C * K; idx += 256) Wn[idx] = W[idx];
    __syncthreads();
    if (tid < K) {
        float s = 0.f;
        for (int c = 0; c < C; ++c) { float v = Wn[c * K + tid]; s = fmaf(v, v, s); }
        colinv[tid] = 1.0f / fmaxf(sqrtf(s), EPS);
    }
    __syncthreads();
    for (int idx = tid; idx < C * K; idx += 256) Wn[idx] *= colinv[idx & (K - 1)];
    // Wn-scaling ordered vs first MAC by the two barriers in the chunk loop.

    const int n  = blockIdx.x >> 5;            // P/PXB = 32 px-blocks per n
    const int p0 = (blockIdx.x & 31) * PXB;
    const int pg = tid & 15;                   // px-group: px = pg*8 .. pg*8+7
    const int kg = tid >> 4;                   // k-group:  k  = kg*4 .. kg*4+3

    const float* xb = x + (size_t)n * C * P + p0;
    const int r0 = tid >> 5;                   // stage row 0..7
    const int c4 = (tid & 31) * 4;             // stage px offset

    float acc[32];
    #pragma unroll
    for (int i = 0; i < 32; ++i) acc[i] = 0.f;
    float ss[8];
    #pragma unroll
    for (int i = 0; i < 8; ++i) ss[i] = 0.f;

    for (int cb = 0; cb < C; cb += BC) {
        __syncthreads();                       // xs reuse guard
        #pragma unroll
        for (int rr = 0; rr < BC; rr += 8) {
            float4 v = *(const float4*)&xb[(size_t)(cb + r0 + rr) * P + c4];
            *(float4*)&xs[(r0 + rr) * XSTR + c4] = v;
        }
        __syncthreads();
        #pragma unroll 4
        for (int cc = 0; cc < BC; ++cc) {
            float4 xa = *(const float4*)&xs[cc * XSTR + pg * 8];
            float4 xc = *(const float4*)&xs[cc * XSTR + pg * 8 + 4];
            float4 wv = *(const float4*)&Wn[(cb + cc) * K + kg * 4];
            ss[0] = fmaf(xa.x, xa.x, ss[0]);
            ss[1] = fmaf(xa.y, xa.y, ss[1]);
            ss[2] = fmaf(xa.z, xa.z, ss[2]);
            ss[3] = fmaf(xa.w, xa.w, ss[3]);
            ss[4] = fmaf(xc.x, xc.x, ss[4]);
            ss[5] = fmaf(xc.y, xc.y, ss[5]);
            ss[6] = fmaf(xc.z, xc.z, ss[6]);
            ss[7] = fmaf(xc.w, xc.w, ss[7]);
            float wj[4] = {wv.x, wv.y, wv.z, wv.w};
            #pragma unroll
            for (int j = 0; j < 4; ++j) {
                acc[j * 8 + 0] = fmaf(wj[j], xa.x, acc[j * 8 + 0]);
                acc[j * 8 + 1] = fmaf(wj[j], xa.y, acc[j * 8 + 1]);
                acc[j * 8 + 2] = fmaf(wj[j], xa.z, acc[j * 8 + 2]);
                acc[j * 8 + 3] = fmaf(wj[j], xa.w, acc[j * 8 + 3]);
                acc[j * 8 + 4] = fmaf(wj[j], xc.x, acc[j * 8 + 4]);
                acc[j * 8 + 5] = fmaf(wj[j], xc.y, acc[j * 8 + 5]);
                acc[j * 8 + 6] = fmaf(wj[j], xc.z, acc[j * 8 + 6]);
                acc[j * 8 + 7] = fmaf(wj[j], xc.w, acc[j * 8 + 7]);
            }
        }
    }

    float inv[8];
    #pragma unroll
    for (int l = 0; l < 8; ++l) inv[l] = 1.0f / fmaxf(sqrtf(ss[l]), EPS);

    if (kg == 0) {                              // 16 threads cover 128 px
        float4 a = {inv[0], inv[1], inv[2], inv[3]};
        float4 b = {inv[4], inv[5], inv[6], inv[7]};
        *(float4*)&invn[(size_t)n * P + p0 + pg * 8]     = a;
        *(float4*)&invn[(size_t)n * P + p0 + pg * 8 + 4] = b;
    }

    float* lp = logits + (size_t)n * K * P + p0 + pg * 8;
    #pragma unroll
    for (int j = 0; j < 4; ++j) {
        const int k = kg * 4 + j;
        float4 o0 = {acc[j*8+0]*inv[0], acc[j*8+1]*inv[1], acc[j*8+2]*inv[2], acc[j*8+3]*inv[3]};
        float4 o1 = {acc[j*8+4]*inv[4], acc[j*8+5]*inv[5], acc[j*8+6]*inv[6], acc[j*8+7]*inv[7]};
        *(float4*)&lp[(size_t)k * P]     = o0;
        *(float4*)&lp[(size_t)k * P + 4] = o1;
    }
}

// ---------------------------------------------------------------------------
// Kernel 2: vlad partial GEMM (R3 internals, PCH=256 -> grid 1024 = 4 blk/CU,
// atomicAdd epilogue). LDS stride 68 (odd-16B) conflict-free for b128.
// ---------------------------------------------------------------------------
constexpr int TP  = 64;
constexpr int STR = 68;
constexpr int PCH = 256;
constexpr int TILES = PCH / TP;

__global__ __launch_bounds__(256) void k_vlad(
    const float* __restrict__ x, const float* __restrict__ logits,
    const float* __restrict__ bias, const float* __restrict__ invn,
    float* __restrict__ vlad_raw, float* __restrict__ Ssum)
{
    __shared__ float sa[K * STR];     // 17 KiB
    __shared__ float xn[C * STR];     // 34 KiB
    __shared__ float red[256];
    __shared__ float biass[K];

    const int tid = threadIdx.x;
    const int n  = blockIdx.x >> 4;            // P/PCH = 16 chunks per n
    const int p0 = (blockIdx.x & 15) * PCH;

    if (tid < K) biass[tid] = bias[tid];

    const int kg = tid >> 4;   // 16 k-groups of 4
    const int cg = tid & 15;   // c = cg + 16*l
    const int si = tid & 63;
    const int sq = tid >> 6;

    float facc[32];
    #pragma unroll
    for (int i = 0; i < 32; ++i) facc[i] = 0.f;
    float Sreg = 0.f;

    for (int t = 0; t < TILES; ++t) {
        const int pb = p0 + t * TP;
        __syncthreads();                       // LDS reuse guard
        #pragma unroll
        for (int r = 0; r < 4; ++r) {          // logits -> sa (float4)
            int idx = r * 256 + tid;
            int k = idx >> 4, f = idx & 15;
            float4 v = *(const float4*)&logits[(size_t)(n * K + k) * P + pb + 4 * f];
            *(float4*)&sa[k * STR + 4 * f] = v;
        }
        #pragma unroll
        for (int r = 0; r < 8; ++r) {          // x * invn -> xn (float4)
            int idx = r * 256 + tid;
            int c = idx >> 4, f = idx & 15;
            float4 v  = *(const float4*)&x[(size_t)(n * C + c) * P + pb + 4 * f];
            float4 iv = *(const float4*)&invn[(size_t)n * P + pb + 4 * f];
            v.x *= iv.x; v.y *= iv.y; v.z *= iv.z; v.w *= iv.w;
            *(float4*)&xn[c * STR + 4 * f] = v;
        }
        __syncthreads();
        // softmax over k, 4 threads per pixel column
        float psum = 0.f;
        #pragma unroll
        for (int kk = 0; kk < 16; ++kk) {
            int k = sq * 16 + kk;
            float e = __expf((sa[k * STR + si] + biass[k]) * ALPHA);
            sa[k * STR + si] = e;
            psum += e;
        }
        red[tid] = psum;
        __syncthreads();
        {
            float r = 1.0f / (red[si] + red[64 + si] + red[128 + si] + red[192 + si]);
            #pragma unroll
            for (int kk = 0; kk < 16; ++kk) sa[(sq * 16 + kk) * STR + si] *= r;
        }
        __syncthreads();
        {
            float s = 0.f;
            #pragma unroll
            for (int ii = 0; ii < 16; ++ii) s += sa[si * STR + sq * 16 + ii];
            Sreg += s;
        }
        // MAC: 4k x 8c x 4px
        #pragma unroll 2
        for (int ii = 0; ii < TP / 4; ++ii) {
            float4 a[4];
            #pragma unroll
            for (int j = 0; j < 4; ++j)
                a[j] = *(const float4*)&sa[(kg * 4 + j) * STR + 4 * ii];
            float4 xv[8];
            #pragma unroll
            for (int l = 0; l < 8; ++l)
                xv[l] = *(const float4*)&xn[(cg + 16 * l) * STR + 4 * ii];
            #pragma unroll
            for (int j = 0; j < 4; ++j)
                #pragma unroll
                for (int l = 0; l < 8; ++l) {
                    facc[j * 8 + l] = fmaf(a[j].x, xv[l].x, facc[j * 8 + l]);
                    facc[j * 8 + l] = fmaf(a[j].y, xv[l].y, facc[j * 8 + l]);
                    facc[j * 8 + l] = fmaf(a[j].z, xv[l].z, facc[j * 8 + l]);
                    facc[j * 8 + l] = fmaf(a[j].w, xv[l].w, facc[j * 8 + l]);
                }
        }
    }

    float* vr = vlad_raw + (size_t)n * K * C;
    #pragma unroll
    for (int j = 0; j < 4; ++j)
        #pragma unroll
        for (int l = 0; l < 8; ++l)
            atomicAdd(&vr[(kg * 4 + j) * C + (cg + 16 * l)], facc[j * 8 + l]);

    red[tid] = Sreg;
    __syncthreads();
    if (sq == 0)
        atomicAdd(&Ssum[n * K + si],
                  red[si] + red[64 + si] + red[128 + si] + red[192 + si]);
}

// ---------------------------------------------------------------------------
// Kernel 3: vlad = l2norm_global(l2norm_c(raw - W[c,k]*S[n,k])). One block/n.
// ---------------------------------------------------------------------------
__global__ __launch_bounds__(256) void k_post(
    const float* __restrict__ vlad_raw, const float* __restrict__ W,
    const float* __restrict__ Ssum, float* __restrict__ out)
{
    __shared__ float red[256];
    const int tid = threadIdx.x;
    const int n = blockIdx.x;
    const int k = tid >> 2;
    const int part = tid & 3;
    const int c0 = part * 32;

    const float* vr = vlad_raw + (size_t)n * K * C + k * C + c0;
    const float Sk = Ssum[n * K + k];
    float v[32];
    float ss = 0.f;
    #pragma unroll
    for (int l = 0; l < 32; ++l) {
        float val = vr[l] - W[(size_t)(c0 + l) * K + k] * Sk;
        v[l] = val;
        ss = fmaf(val, val, ss);
    }
    ss += __shfl_xor(ss, 1);
    ss += __shfl_xor(ss, 2);
    const float inv1 = 1.0f / fmaxf(sqrtf(ss), EPS);
    float ss2 = 0.f;
    #pragma unroll
    for (int l = 0; l < 32; ++l) { v[l] *= inv1; ss2 = fmaf(v[l], v[l], ss2); }
    red[tid] = ss2;
    __syncthreads();
    for (int s = 128; s > 0; s >>= 1) {
        if (tid < s) red[tid] += red[tid + s];
        __syncthreads();
    }
    const float inv2 = 1.0f / fmaxf(sqrtf(red[0]), EPS);
    float* op = out + (size_t)n * K * C + k * C + c0;
    #pragma unroll
    for (int l = 0; l < 32; ++l) op[l] = v[l] * inv2;
}

// ---------------------------------------------------------------------------
extern "C" void kernel_launch(void* const* d_in, const int* in_sizes, int n_in,
                              void* d_out, int out_size, void* d_ws, size_t ws_size,
                              hipStream_t stream)
{
    const float* x    = (const float*)d_in[0];
    const float* W    = (const float*)d_in[1];
    const float* bias = (const float*)d_in[2];

    float* out_vlad   = (float*)d_out;                       // N*K*C
    float* out_logits = (float*)d_out + (size_t)N * K * C;   // N*K*P

    float* invn     = (float*)d_ws;                          // N*P
    float* Ssum     = invn + (size_t)N * P;                  // N*K
    float* vlad_raw = Ssum + (size_t)N * K;                  // N*K*C

    hipMemsetAsync(Ssum, 0, (size_t)(N * K + N * K * C) * sizeof(float), stream);
    k_logits<<<dim3(N * 32), dim3(256), 0, stream>>>(x, W, out_logits, invn);
    k_vlad<<<dim3(N * (P / PCH)), dim3(256), 0, stream>>>(x, out_logits, bias, invn, vlad_raw, Ssum);
    k_post<<<dim3(N), dim3(256), 0, stream>>>(vlad_raw, W, Ssum, out_vlad);
}

// Round 5
// 251.561 us; speedup vs baseline: 3.0422x; 1.2775x over previous
//
#include <hip/hip_runtime.h>
#include <math.h>

#define ALPHA 50.0f
#define EPS 1e-12f

constexpr int N = 64, C = 128, P = 4096, K = 64;
constexpr int NCH2 = 8;           // partial groups (one per block per n)

typedef short short8_t __attribute__((ext_vector_type(8)));
typedef short short4_t __attribute__((ext_vector_type(4)));
typedef float f4 __attribute__((ext_vector_type(4)));

__device__ __forceinline__ unsigned short f2bf(float f) {
    union { float f; unsigned u; } v; v.f = f;
    unsigned r = (v.u + 0x7FFFu + ((v.u >> 16) & 1u)) >> 16;   // RNE
    return (unsigned short)r;
}

// ---------------------------------------------------------------------------
// Prep: WnT[k][c] = bf16(W[c][k] / max(||W[:,k]||, eps)). One block.
// ---------------------------------------------------------------------------
__global__ __launch_bounds__(256) void k_prep(
    const float* __restrict__ W, unsigned short* __restrict__ wnT)
{
    __shared__ float Wl[C * 65];
    __shared__ float cinv[K];
    const int tid = threadIdx.x;
    for (int idx = tid; idx < C * K; idx += 256) {
        int c = idx >> 6, k = idx & 63;
        Wl[c * 65 + k] = W[idx];
    }
    __syncthreads();
    if (tid < K) {
        float s = 0.f;
        for (int c = 0; c < C; ++c) { float v = Wl[c * 65 + tid]; s = fmaf(v, v, s); }
        cinv[tid] = 1.0f / fmaxf(sqrtf(s), EPS);
    }
    __syncthreads();
    for (int idx = tid; idx < K * C; idx += 256) {
        int k = idx >> 7, c = idx & 127;
        wnT[idx] = f2bf(Wl[c * 65 + k] * cinv[k]);
    }
}

// ---------------------------------------------------------------------------
// Fused: per block = (n, 512-px strip) in 8 chunks of 64 px.
//   stage raw x -> bf16 xsT[px][c] (GEMM1-B) + xsN[c][px] (GEMM2-B), ssq->inv
//   GEMM1 (MFMA): rawlogit[k][px] = Wn^T . x ; logits = rawlogit*inv -> out+LDS
//   softmax over k in LDS ; sa2 = sa*inv (bf16) ; S partial
//   GEMM2 (MFMA): acc2[k][c] += sa2 . x_raw  (accumulated across 8 chunks)
// No atomics; partials per block -> ws.
// ---------------------------------------------------------------------------
__global__ __launch_bounds__(256) void k_fused(
    const float* __restrict__ x, const unsigned short* __restrict__ wnT,
    const float* __restrict__ bias, float* __restrict__ logits,
    float* __restrict__ vlad_part, float* __restrict__ Spart)
{
    __shared__ unsigned short xsT[64 * 136];   // [px][c] bf16, stride 136 (68 dw ≡ 4 mod 32)
    __shared__ unsigned short xsN[128 * 76];   // [c][px] bf16, stride 76 (38 dw ≡ 6 mod 32)
    __shared__ float          saf[64 * 66];    // [k][px] fp32 (also ssq-reduce overlay)
    __shared__ unsigned short sa2s[64 * 72];   // [k][px] bf16, stride 72 (36 dw)
    __shared__ float invs[64];
    __shared__ float rfin[64];
    __shared__ float red[256];
    __shared__ float biass[64];

    const int tid  = threadIdx.x;
    const int n    = blockIdx.x >> 3;
    const int blk8 = blockIdx.x & 7;
    const int pbase = blk8 * 512;

    const int w = tid >> 6, lane = tid & 63;
    const int q = lane >> 4, l15 = lane & 15;
    const int pxg = tid & 15, cg = tid >> 4;   // staging roles
    const int px = tid & 63, sq = tid >> 6;    // softmax roles

    if (tid < K) biass[tid] = bias[tid];

    // A1 fragments (Wn^T rows k=16w+l15, c-slices) — constant across chunks, from L2
    short8_t af[4];
    #pragma unroll
    for (int c0 = 0; c0 < 4; ++c0)
        af[c0] = *(const short8_t*)&wnT[(16 * w + l15) * 128 + c0 * 32 + 8 * q];

    f4 acc2[8];
    #pragma unroll
    for (int ct = 0; ct < 8; ++ct) acc2[ct] = (f4){0.f, 0.f, 0.f, 0.f};
    float Sreg = 0.f;

    for (int ch = 0; ch < 8; ++ch) {
        const int p0 = pbase + ch * 64;
        __syncthreads();                         // LDS reuse guard vs prev chunk

        // ---- global load (fp32) + sum-of-squares + bf16 staging ----
        const float* xb = x + (size_t)n * C * P + p0 + 4 * pxg;
        float4 v[8];
        #pragma unroll
        for (int j = 0; j < 8; ++j) v[j] = *(const float4*)&xb[(size_t)(8 * cg + j) * P];
        const float* vf = (const float*)v;

        float pss[4] = {0.f, 0.f, 0.f, 0.f};
        #pragma unroll
        for (int j = 0; j < 8; ++j)
            #pragma unroll
            for (int i = 0; i < 4; ++i)
                pss[i] = fmaf(vf[j * 4 + i], vf[j * 4 + i], pss[i]);
        float* red2 = saf;                       // overlay (saf dead here)
        #pragma unroll
        for (int i = 0; i < 4; ++i) red2[(4 * pxg + i) * 16 + cg] = pss[i];

        #pragma unroll
        for (int i = 0; i < 4; ++i) {            // xsT: px-row, 8 contiguous c
            short8_t t;
            #pragma unroll
            for (int j = 0; j < 8; ++j) t[j] = (short)f2bf(vf[j * 4 + i]);
            *(short8_t*)&xsT[(4 * pxg + i) * 136 + 8 * cg] = t;
        }
        #pragma unroll
        for (int j = 0; j < 8; ++j) {            // xsN: c-row, 4 contiguous px
            short4_t t4;
            #pragma unroll
            for (int i = 0; i < 4; ++i) t4[i] = (short)f2bf(vf[j * 4 + i]);
            *(short4_t*)&xsN[(8 * cg + j) * 76 + 4 * pxg] = t4;
        }
        __syncthreads();
        if (tid < 64) {
            float s = 0.f;
            #pragma unroll
            for (int g = 0; g < 16; ++g) s += red2[tid * 16 + g];
            invs[tid] = 1.0f / fmaxf(sqrtf(s), EPS);
        }
        __syncthreads();

        // ---- GEMM1: rawlogit[k][px] ----
        f4 acc1[4];
        #pragma unroll
        for (int t = 0; t < 4; ++t) acc1[t] = (f4){0.f, 0.f, 0.f, 0.f};
        #pragma unroll
        for (int c0 = 0; c0 < 4; ++c0)
            #pragma unroll
            for (int pxt = 0; pxt < 4; ++pxt) {
                short8_t bf = *(const short8_t*)&xsT[(pxt * 16 + l15) * 136 + c0 * 32 + 8 * q];
                acc1[pxt] = __builtin_amdgcn_mfma_f32_16x16x32_bf16(af[c0], bf, acc1[pxt], 0, 0, 0);
            }

        // ---- logits = raw * inv[px] -> global out + saf ----
        float* lgp = logits + (size_t)n * K * P + p0;
        #pragma unroll
        for (int pxt = 0; pxt < 4; ++pxt) {
            const int pxl = pxt * 16 + l15;
            const float iv = invs[pxl];
            #pragma unroll
            for (int r = 0; r < 4; ++r) {
                const int k = 16 * w + 4 * q + r;
                const float lv = acc1[pxt][r] * iv;
                saf[k * 66 + pxl] = lv;
                lgp[(size_t)k * P + pxl] = lv;
            }
        }
        __syncthreads();

        // ---- softmax over k (col = px), all 256 threads ----
        float ps = 0.f;
        #pragma unroll
        for (int kk = 0; kk < 16; ++kk) {
            const int k = sq * 16 + kk;
            float e = __expf((saf[k * 66 + px] + biass[k]) * ALPHA);
            saf[k * 66 + px] = e;
            ps += e;
        }
        red[tid] = ps;
        __syncthreads();
        if (tid < 64)
            rfin[tid] = 1.0f / (red[tid] + red[64 + tid] + red[128 + tid] + red[192 + tid]);
        __syncthreads();

        // ---- S partial (row k = tid&63, px segment sq) + sa2 = sa*inv bf16 ----
        {
            float s = 0.f;
            #pragma unroll
            for (int ii = 0; ii < 16; ++ii)
                s += saf[px * 66 + sq * 16 + ii] * rfin[sq * 16 + ii];
            Sreg += s;
        }
        {
            const float rf = rfin[px] * invs[px];
            #pragma unroll
            for (int kk = 0; kk < 16; ++kk) {
                const int k = sq * 16 + kk;
                sa2s[k * 72 + px] = f2bf(saf[k * 66 + px] * rf);
            }
        }
        __syncthreads();

        // ---- GEMM2: acc2[k][c] += sa2 . x_raw ----
        short8_t a2[2];
        #pragma unroll
        for (int kit = 0; kit < 2; ++kit)
            a2[kit] = *(const short8_t*)&sa2s[(16 * w + l15) * 72 + kit * 32 + 8 * q];
        #pragma unroll
        for (int ct = 0; ct < 8; ++ct)
            #pragma unroll
            for (int kit = 0; kit < 2; ++kit) {
                const unsigned short* bp = &xsN[(ct * 16 + l15) * 76 + kit * 32 + 8 * q];
                short4_t b0 = *(const short4_t*)bp;
                short4_t b1 = *(const short4_t*)(bp + 4);
                short8_t bb;
                bb[0] = b0[0]; bb[1] = b0[1]; bb[2] = b0[2]; bb[3] = b0[3];
                bb[4] = b1[0]; bb[5] = b1[1]; bb[6] = b1[2]; bb[7] = b1[3];
                acc2[ct] = __builtin_amdgcn_mfma_f32_16x16x32_bf16(a2[kit], bb, acc2[ct], 0, 0, 0);
            }
    }

    // ---- epilogue: per-block partials (no atomics) ----
    float* vp = vlad_part + ((size_t)blk8 * N + n) * (size_t)(K * C);
    #pragma unroll
    for (int ct = 0; ct < 8; ++ct)
        #pragma unroll
        for (int r = 0; r < 4; ++r)
            vp[(16 * w + 4 * q + r) * C + ct * 16 + l15] = acc2[ct][r];

    red[tid] = Sreg;
    __syncthreads();
    if (tid < 64)
        Spart[((size_t)blk8 * N + n) * K + tid] =
            red[tid] + red[64 + tid] + red[128 + tid] + red[192 + tid];
}

// ---------------------------------------------------------------------------
// Post: reduce 8 partials, subtract W*S, intra-norm (c), global norm. 1 blk/n.
// ---------------------------------------------------------------------------
__global__ __launch_bounds__(256) void k_post(
    const float* __restrict__ vlad_part, const float* __restrict__ W,
    const float* __restrict__ Spart, float* __restrict__ out)
{
    __shared__ float red[256];
    const int tid = threadIdx.x;
    const int n = blockIdx.x;
    const int k = tid >> 2;
    const int part = tid & 3;
    const int c0 = part * 32;

    float Sk = 0.f;
    #pragma unroll
    for (int ch = 0; ch < NCH2; ++ch) Sk += Spart[(size_t)(ch * N + n) * K + k];

    float v[32];
    #pragma unroll
    for (int l = 0; l < 32; ++l) v[l] = 0.f;
    #pragma unroll
    for (int ch = 0; ch < NCH2; ++ch) {
        const float* vp = vlad_part + ((size_t)(ch * N + n) * K + k) * C + c0;
        #pragma unroll
        for (int l4 = 0; l4 < 8; ++l4) {
            float4 t = *(const float4*)&vp[4 * l4];
            v[4 * l4 + 0] += t.x; v[4 * l4 + 1] += t.y;
            v[4 * l4 + 2] += t.z; v[4 * l4 + 3] += t.w;
        }
    }

    float ss = 0.f;
    #pragma unroll
    for (int l = 0; l < 32; ++l) {
        float val = v[l] - W[(size_t)(c0 + l) * K + k] * Sk;
        v[l] = val;
        ss = fmaf(val, val, ss);
    }
    ss += __shfl_xor(ss, 1);
    ss += __shfl_xor(ss, 2);
    const float inv1 = 1.0f / fmaxf(sqrtf(ss), EPS);
    float ss2 = 0.f;
    #pragma unroll
    for (int l = 0; l < 32; ++l) { v[l] *= inv1; ss2 = fmaf(v[l], v[l], ss2); }
    red[tid] = ss2;
    __syncthreads();
    for (int s = 128; s > 0; s >>= 1) {
        if (tid < s) red[tid] += red[tid + s];
        __syncthreads();
    }
    const float inv2 = 1.0f / fmaxf(sqrtf(red[0]), EPS);
    float* op = out + (size_t)n * K * C + k * C + c0;
    #pragma unroll
    for (int l = 0; l < 32; ++l) op[l] = v[l] * inv2;
}

// ---------------------------------------------------------------------------
extern "C" void kernel_launch(void* const* d_in, const int* in_sizes, int n_in,
                              void* d_out, int out_size, void* d_ws, size_t ws_size,
                              hipStream_t stream)
{
    const float* x    = (const float*)d_in[0];
    const float* W    = (const float*)d_in[1];
    const float* bias = (const float*)d_in[2];

    float* out_vlad   = (float*)d_out;                       // N*K*C
    float* out_logits = (float*)d_out + (size_t)N * K * C;   // N*K*P

    unsigned short* wnT = (unsigned short*)d_ws;                          // 16 KiB
    float* Spart        = (float*)((char*)d_ws + 32768);                  // 128 KiB
    float* vlad_part    = (float*)((char*)d_ws + 32768 + 131072);         // 16 MiB

    k_prep<<<dim3(1), dim3(256), 0, stream>>>(W, wnT);
    k_fused<<<dim3(N * NCH2), dim3(256), 0, stream>>>(x, wnT, bias, out_logits, vlad_part, Spart);
    k_post<<<dim3(N), dim3(256), 0, stream>>>(vlad_part, W, Spart, out_vlad);
}